// Round 13
// baseline (536.100 us; speedup 1.0000x reference)
//
#include <hip/hip_runtime.h>
#include <hip/hip_bf16.h>

// GAT forward: N=8192, IN=512, HID=256, OUT=64.
// w_ij = A_ij * max( e^{s1_i} e^{s2_j}, e^{0.2 s1_i} e^{0.2 s2_j} )
// Round 13: k_attn stages 32KB (2 K-step chunks) per barrier -> 32 lockstep sync
// points instead of 64; 16 MFMAs + 16 ds_reads between barriers. LDS 2x32KB,
// 2 blocks/CU (128KB), occupancy unchanged. All else = r12 (best, 533.3).

typedef float f32x4 __attribute__((ext_vector_type(4)));
typedef short s16x8 __attribute__((ext_vector_type(8)));

#define NN 8192
#define INDIM 512
#define HIDD 256
#define OUTD 64

static __device__ __forceinline__ short f2bf(float x) {
    __hip_bfloat16 h = __float2bfloat16(x);
    return __builtin_bit_cast(short, h);
}

static __device__ __forceinline__ void split_bf(float x, short& hi, short& lo) {
    short h = f2bf(x);
    unsigned int hb = ((unsigned int)(unsigned short)h) << 16;
    float hf = __builtin_bit_cast(float, hb);
    hi = h;
    lo = f2bf(x - hf);
}

// ---------------- kernel A: pack A (8192x8192 int32) -> bitmask ------------------------
// dword idx i*256 + ks*64 + q*16 + kk4, byte kkq, bit j <-> col = ks*2048+(kk4*4+kkq)*32+q*8+j
__global__ void __launch_bounds__(256)
k_packA(const int* __restrict__ A, unsigned int* __restrict__ Apk) {
    const int i = blockIdx.x;
    const int t = threadIdx.x;               // t = ks*64 + q*16 + kk0
    const int ks = t >> 6, q = (t >> 4) & 3, kk0 = t & 15;
    const int* Ar = A + (size_t)i * NN;
    unsigned int out = 0;
#pragma unroll
    for (int kkq = 0; kkq < 4; ++kkq) {
        const int kk = kk0 * 4 + kkq;
        const int c0 = ks * 2048 + kk * 32 + q * 8;
        int4 v0 = *(const int4*)(Ar + c0);
        int4 v1 = *(const int4*)(Ar + c0 + 4);
        unsigned int b = 0;
        b |= (v0.x > 0) ? 1u : 0u;
        b |= (v0.y > 0) ? 2u : 0u;
        b |= (v0.z > 0) ? 4u : 0u;
        b |= (v0.w > 0) ? 8u : 0u;
        b |= (v1.x > 0) ? 16u : 0u;
        b |= (v1.y > 0) ? 32u : 0u;
        b |= (v1.z > 0) ? 64u : 0u;
        b |= (v1.w > 0) ? 128u : 0u;
        out |= b << (kkq * 8);
    }
    Apk[(size_t)i * 256 + t] = out;
}

// ---------------- kernel 0: W1 (512x256 f32) -> W1^T hi/lo bf16 [256][512] -------------
__global__ void k_splitW1(const float* __restrict__ W1,
                          short* __restrict__ W1Thi, short* __restrict__ W1Tlo) {
    int t = blockIdx.x * 256 + threadIdx.x;   // t = n*512 + k
    int n = t >> 9;
    int k = t & 511;
    float x = W1[k * 256 + n];
    short hi, lo; split_bf(x, hi, lo);
    W1Thi[t] = hi;
    W1Tlo[t] = lo;
}

// ---------------- kernel 1: H1 = X@W1+b1 (split-bf16 MFMA, column-split) ---------------
// Grid 1024 = 512 row-tiles x 2 col-halves -> 4 blocks/CU (4 waves/SIMD TLP).
__global__ void __launch_bounds__(256, 4)
k_h1(const float* __restrict__ X, const short* __restrict__ W1Thi,
     const short* __restrict__ W1Tlo, const float* __restrict__ b1,
     const float* __restrict__ avec, unsigned short* __restrict__ H1TB,
     float* __restrict__ s1w, float* __restrict__ s2w) {
    __shared__ float s1p[4][16];
    __shared__ float s2p[4][16];
    const int tid = threadIdx.x;
    const int wn = tid >> 6, lane = tid & 63;
    const int q = lane >> 4, m16 = lane & 15;
    const int rt = blockIdx.x >> 1;
    const int ch = blockIdx.x & 1;
    const int i0 = rt * 16;
    const int irow = i0 + m16;
    const int colbase = ch * 128 + wn * 32;

    f32x4 zero4 = {0.f, 0.f, 0.f, 0.f};
    f32x4 acc[2];
#pragma unroll
    for (int nt = 0; nt < 2; ++nt) acc[nt] = zero4;

    const float* Xrow = X + (size_t)irow * INDIM;
    for (int kk = 0; kk < INDIM; kk += 32) {
        const int k0 = kk + q * 8;
        float4 xa = *(const float4*)(Xrow + k0);
        float4 xb = *(const float4*)(Xrow + k0 + 4);
        float xs[8] = {xa.x, xa.y, xa.z, xa.w, xb.x, xb.y, xb.z, xb.w};
        s16x8 ahi, alo;
#pragma unroll
        for (int j = 0; j < 8; ++j) { short h, l; split_bf(xs[j], h, l); ahi[j] = h; alo[j] = l; }
#pragma unroll
        for (int nt = 0; nt < 2; ++nt) {
            const int n = colbase + nt * 16 + m16;
            s16x8 bhi = *(const s16x8*)(W1Thi + n * INDIM + k0);
            s16x8 blo = *(const s16x8*)(W1Tlo + n * INDIM + k0);
            acc[nt] = __builtin_amdgcn_mfma_f32_16x16x32_bf16(ahi, bhi, acc[nt], 0, 0, 0);
            acc[nt] = __builtin_amdgcn_mfma_f32_16x16x32_bf16(ahi, blo, acc[nt], 0, 0, 0);
            acc[nt] = __builtin_amdgcn_mfma_f32_16x16x32_bf16(alo, bhi, acc[nt], 0, 0, 0);
        }
    }

    float p1[4] = {0.f, 0.f, 0.f, 0.f};
    float p2[4] = {0.f, 0.f, 0.f, 0.f};
    const int rowbase = i0 + q * 4;             // C rows: (lane>>4)*4 + r
    const int chunk = rowbase >> 5, win = rowbase & 31;
#pragma unroll
    for (int nt = 0; nt < 2; ++nt) {
        const int col = colbase + nt * 16 + m16;
        const float b1v = b1[col];
        const float a1v = avec[col];
        const float a2v = avec[HIDD + col];
        float v0 = acc[nt][0] + b1v;
        float v1 = acc[nt][1] + b1v;
        float v2 = acc[nt][2] + b1v;
        float v3 = acc[nt][3] + b1v;
        ushort4 us;
        us.x = (unsigned short)f2bf(v0);
        us.y = (unsigned short)f2bf(v1);
        us.z = (unsigned short)f2bf(v2);
        us.w = (unsigned short)f2bf(v3);
        *(ushort4*)(H1TB + (size_t)chunk * 8192 + col * 32 + win) = us;
        p1[0] += v0 * a1v; p1[1] += v1 * a1v; p1[2] += v2 * a1v; p1[3] += v3 * a1v;
        p2[0] += v0 * a2v; p2[1] += v1 * a2v; p2[2] += v2 * a2v; p2[3] += v3 * a2v;
    }
#pragma unroll
    for (int off = 1; off < 16; off <<= 1) {
#pragma unroll
        for (int r = 0; r < 4; ++r) {
            p1[r] += __shfl_xor(p1[r], off);
            p2[r] += __shfl_xor(p2[r], off);
        }
    }
    if (m16 == 0) {
#pragma unroll
        for (int r = 0; r < 4; ++r) {
            s1p[wn][q * 4 + r] = p1[r];
            s2p[wn][q * 4 + r] = p2[r];
        }
    }
    __syncthreads();
    if (tid < 16) {
        const int i = i0 + tid;
        float s1 = (s1p[0][tid] + s1p[1][tid]) + (s1p[2][tid] + s1p[3][tid]);
        float s2 = (s2p[0][tid] + s2p[1][tid]) + (s2p[2][tid] + s2p[3][tid]);
        atomicAdd(&s1w[i], s1);
        atomicAdd(&s2w[i], s2);
    }
}

// ---------------- kernel 1b: exp factors from s1/s2 totals -----------------------------
__global__ void __launch_bounds__(256)
k_uv(const float* __restrict__ s1w, const float* __restrict__ s2w,
     float* __restrict__ alw, float* __restrict__ bew, float* __restrict__ uvw) {
    const int i = blockIdx.x * 256 + threadIdx.x;
    const float s1 = s1w[i], s2 = s2w[i];
    alw[i] = expf(s1);
    bew[i] = expf(0.2f * s1);
    uvw[2 * i]     = expf(s2);
    uvw[2 * i + 1] = expf(0.2f * s2);
}

// ---------------- kernel 2: H2acc += W @ H1 (BK=64: 2 K-steps per barrier) -------------
// Grid 512, block 512 = 8 waves (wm = wave>>1: 4 row-groups, wn = wave&1: hid half).
// Each iteration it=0..31: wv-gen for K-steps 2it,2it+1 -> ONE barrier cluster ->
// stage 32KB (2 chunks) into buf[it+1&1] + uv prefetch -> 16 MFMAs on buf[it&1].
// vmcnt: barrier waits vmcnt(1) at pair0 (A-prefetch in flight) else vmcnt(0).
// XCD-pinned ks; swizzled LDS (conflict-free, verified r7). LDS 64KB, 2 blk/CU.
__global__ void __launch_bounds__(512, 4)
k_attn(const unsigned int* __restrict__ Apk, const unsigned short* __restrict__ H1TB,
       const float* __restrict__ alw, const float* __restrict__ bew,
       const float* __restrict__ uvw,
       float* __restrict__ H2acc, float* __restrict__ Zw) {
    __shared__ unsigned short tile[2][16384];  // 64 KB: 2 x 2chunk x [256 hid][32 j]

    const int tid = threadIdx.x;
    const int wave = tid >> 6, lane = tid & 63;
    const int q = lane >> 4, m16 = lane & 15;
    const int wm = wave >> 1, wn = wave & 1;
    const int bid = blockIdx.x;
    const int xcd = bid & 7;
    const int ks = xcd >> 1;
    const int mb = ((bid >> 3) << 1) | (xcd & 1);          // 0..127, 64 rows each
    const int i = mb * 64 + wm * 16 + m16;
    const float al = alw[i], be = bew[i];

    // staging source: pre-swizzled global offset (inverse of read-side XOR).
    // XOR acts on ushort-idx bits [3:4]<->[6:7]; c*4096 offsets (bit>=12) safe.
    const int tswz = tid ^ ((tid >> 3) & 3);
    const unsigned short* gp = H1TB + (size_t)ks * 64 * 8192 + tswz * 8;
    __attribute__((address_space(3))) unsigned short* tl =
        (__attribute__((address_space(3))) unsigned short*)&tile[0][0];

    const unsigned int* Ab = Apk + (size_t)i * 256 + ks * 64 + q * 16;
    const float* uvp = uvw + 2 * (ks * 2048 + q * 8);

    // read-side: h = wn*128 + nt*16 + m16; xor term is nt-independent
    const int hb0 = wn * 128 + m16;
    const int qx = (q * 8) ^ (((hb0 >> 1) & 3) << 3);   // swizzled j-offset

    f32x4 zero4 = {0.f, 0.f, 0.f, 0.f};
    f32x4 acc[8];
#pragma unroll
    for (int nt = 0; nt < 8; ++nt) acc[nt] = zero4;
    float zacc = 0.f;

    // ---- prologue: stage pair 0 (32KB) into buf 0, uv pair 0, A dword 0 ----
#pragma unroll
    for (int c = 0; c < 4; ++c)
        __builtin_amdgcn_global_load_lds(
            (const __attribute__((address_space(1))) void*)(gp + c * 4096),
            (__attribute__((address_space(3))) void*)(tl + c * 4096 + tid * 8),
            16, 0, 0);
    gp += 16384;

    float4 uv0 = *(const float4*)(uvp);
    float4 uv1 = *(const float4*)(uvp + 4);
    float4 uv2 = *(const float4*)(uvp + 8);
    float4 uv3 = *(const float4*)(uvp + 12);
    float4 uv4 = *(const float4*)(uvp + 64);
    float4 uv5 = *(const float4*)(uvp + 68);
    float4 uv6 = *(const float4*)(uvp + 72);
    float4 uv7 = *(const float4*)(uvp + 76);
    uvp += 128;
    unsigned int a4 = Ab[0];

    for (int kt = 0; kt < 16; ++kt) {
        // prefetch next A dword (kept in flight across the pair-0 barrier)
        unsigned int a4n = Ab[(kt + 1) & 15];
#pragma unroll
        for (int p = 0; p < 2; ++p) {
            const int it = kt * 2 + p;                     // 0..31
            const unsigned int ab0 = a4 >> ((p * 2) * 8);      // K-step 2it
            const unsigned int ab1 = a4 >> ((p * 2 + 1) * 8);  // K-step 2it+1

            // ---- weight generation for both K-steps ----
            float w0[8], w1[8];
            w0[0] = (ab0 & 1u)   ? fmaxf(al * uv0.x, be * uv0.y) : 0.f;
            w0[1] = (ab0 & 2u)   ? fmaxf(al * uv0.z, be * uv0.w) : 0.f;
            w0[2] = (ab0 & 4u)   ? fmaxf(al * uv1.x, be * uv1.y) : 0.f;
            w0[3] = (ab0 & 8u)   ? fmaxf(al * uv1.z, be * uv1.w) : 0.f;
            w0[4] = (ab0 & 16u)  ? fmaxf(al * uv2.x, be * uv2.y) : 0.f;
            w0[5] = (ab0 & 32u)  ? fmaxf(al * uv2.z, be * uv2.w) : 0.f;
            w0[6] = (ab0 & 64u)  ? fmaxf(al * uv3.x, be * uv3.y) : 0.f;
            w0[7] = (ab0 & 128u) ? fmaxf(al * uv3.z, be * uv3.w) : 0.f;
            w1[0] = (ab1 & 1u)   ? fmaxf(al * uv4.x, be * uv4.y) : 0.f;
            w1[1] = (ab1 & 2u)   ? fmaxf(al * uv4.z, be * uv4.w) : 0.f;
            w1[2] = (ab1 & 4u)   ? fmaxf(al * uv5.x, be * uv5.y) : 0.f;
            w1[3] = (ab1 & 8u)   ? fmaxf(al * uv5.z, be * uv5.w) : 0.f;
            w1[4] = (ab1 & 16u)  ? fmaxf(al * uv6.x, be * uv6.y) : 0.f;
            w1[5] = (ab1 & 32u)  ? fmaxf(al * uv6.z, be * uv6.w) : 0.f;
            w1[6] = (ab1 & 64u)  ? fmaxf(al * uv7.x, be * uv7.y) : 0.f;
            w1[7] = (ab1 & 128u) ? fmaxf(al * uv7.z, be * uv7.w) : 0.f;
            zacc += (w0[0] + w0[1] + w0[2] + w0[3]) + (w0[4] + w0[5] + w0[6] + w0[7]);
            zacc += (w1[0] + w1[1] + w1[2] + w1[3]) + (w1[4] + w1[5] + w1[6] + w1[7]);
            s16x8 af0, af1;
#pragma unroll
            for (int j = 0; j < 8; ++j) { af0[j] = f2bf(w0[j]); af1[j] = f2bf(w1[j]); }

            // ---- barrier cluster: drain stage(it) (issued one iteration ago) ----
            __builtin_amdgcn_sched_barrier(0);
            if (p == 0) asm volatile("s_waitcnt vmcnt(1)" ::: "memory");
            else        asm volatile("s_waitcnt vmcnt(0)" ::: "memory");
            __builtin_amdgcn_s_barrier();
            __builtin_amdgcn_sched_barrier(0);

            if (it < 31) {
                // uv pair (it+1) first, then stage pair (it+1) into buf^1
                uv0 = *(const float4*)(uvp);
                uv1 = *(const float4*)(uvp + 4);
                uv2 = *(const float4*)(uvp + 8);
                uv3 = *(const float4*)(uvp + 12);
                uv4 = *(const float4*)(uvp + 64);
                uv5 = *(const float4*)(uvp + 68);
                uv6 = *(const float4*)(uvp + 72);
                uv7 = *(const float4*)(uvp + 76);
                uvp += 128;
                const int nb = ((it + 1) & 1) * 16384;
#pragma unroll
                for (int c = 0; c < 4; ++c)
                    __builtin_amdgcn_global_load_lds(
                        (const __attribute__((address_space(1))) void*)(gp + c * 4096),
                        (__attribute__((address_space(3))) void*)(tl + nb + c * 4096 + tid * 8),
                        16, 0, 0);
                gp += 16384;
            }

            // ---- MFMA phases on buf[it&1]: half 0 with af0, half 1 with af1 ----
            const unsigned short* tb = &tile[it & 1][0];
#pragma unroll
            for (int nt = 0; nt < 8; ++nt) {
                s16x8 bfv = *(const s16x8*)(tb + (hb0 + nt * 16) * 32 + qx);
                acc[nt] = __builtin_amdgcn_mfma_f32_16x16x32_bf16(af0, bfv, acc[nt], 0, 0, 0);
            }
#pragma unroll
            for (int nt = 0; nt < 8; ++nt) {
                s16x8 bfv = *(const s16x8*)(tb + 8192 + (hb0 + nt * 16) * 32 + qx);
                acc[nt] = __builtin_amdgcn_mfma_f32_16x16x32_bf16(af1, bfv, acc[nt], 0, 0, 0);
            }
        }
        a4 = a4n;
    }

    // Z row-sum: reduce across q groups; wn==0 waves (wm 0..3) cover all 64 rows.
    zacc += __shfl_xor(zacc, 16);
    zacc += __shfl_xor(zacc, 32);
    if (wn == 0 && q == 0) atomicAdd(&Zw[i], zacc);

    const int rowbase = mb * 64 + wm * 16 + q * 4;
#pragma unroll
    for (int nt = 0; nt < 8; ++nt) {
        const int col = wn * 128 + nt * 16 + m16;
#pragma unroll
        for (int r = 0; r < 4; ++r)
            atomicAdd(&H2acc[(size_t)(rowbase + r) * HIDD + col], acc[nt][r]);
    }
}

// ---------------- kernel 3: out = sigmoid((H2acc/Z) @ Omega + beta) --------------------
// Grid 512 (16 rows/block, 2 blocks/CU by 64KB LDS) for 2x TLP on the H2acc read.
__global__ void __launch_bounds__(256)
k_out(const float* __restrict__ H2acc, const float* __restrict__ Zw,
      const float* __restrict__ Omega, const float* __restrict__ beta,
      float* __restrict__ out) {
    __shared__ float om[HIDD * OUTD];  // 64 KB
    const int tid = threadIdx.x;
    for (int idx = tid; idx < HIDD * OUTD; idx += 256) om[idx] = Omega[idx];
    __syncthreads();
    const int wave = tid >> 6, o = tid & 63;
    const float bv = beta[o];
    for (int rr = 0; rr < 4; ++rr) {
        const int i = blockIdx.x * 16 + wave * 4 + rr;
        const float4* H2v = (const float4*)(H2acc + (size_t)i * HIDD);
        float acc = 0.f;
#pragma unroll 4
        for (int c4 = 0; c4 < 64; ++c4) {
            float4 h = H2v[c4];
            const int cb = c4 * 4;
            acc = fmaf(h.x, om[(cb + 0) * OUTD + o], acc);
            acc = fmaf(h.y, om[(cb + 1) * OUTD + o], acc);
            acc = fmaf(h.z, om[(cb + 2) * OUTD + o], acc);
            acc = fmaf(h.w, om[(cb + 3) * OUTD + o], acc);
        }
        const float zinv = 1.0f / Zw[i];
        const float logit = acc * zinv + bv;
        out[(size_t)i * OUTD + o] = 1.0f / (1.0f + expf(-logit));
    }
}

extern "C" void kernel_launch(void* const* d_in, const int* in_sizes, int n_in,
                              void* d_out, int out_size, void* d_ws, size_t ws_size,
                              hipStream_t stream) {
    const float* X     = (const float*)d_in[0];
    const int*   A     = (const int*)d_in[1];
    const float* W1    = (const float*)d_in[2];
    const float* b1    = (const float*)d_in[3];
    const float* avec  = (const float*)d_in[4];
    const float* Omega = (const float*)d_in[5];
    const float* beta  = (const float*)d_in[6];
    float* out = (float*)d_out;

    char* ws = (char*)d_ws;
    unsigned short* H1TB = (unsigned short*)(ws + 0);       // 4,194,304
    short* W1Thi = (short*)(ws + 4194304);                  // 262,144
    short* W1Tlo = (short*)(ws + 4456448);                  // 262,144
    float* s1w   = (float*)(ws + 4718592);                  // 32,768
    float* s2w   = (float*)(ws + 4751360);                  // 32,768
    float* alw   = (float*)(ws + 4784128);                  // 32,768
    float* bew   = (float*)(ws + 4816896);                  // 32,768
    float* uvw   = (float*)(ws + 4849664);                  // 65,536
    float* Zw    = (float*)(ws + 4915200);                  // 32,768
    float* H2acc = (float*)(ws + 4947968);                  // 8,388,608
    unsigned int* Apk = (unsigned int*)(ws + 13336576);     // 8,388,608 (end 21,725,184)

    // zero s1w..H2acc (8,617,984 B): covers s1w/s2w atomics, Zw, H2acc.
    hipMemsetAsync(s1w, 0, 8617984, stream);

    k_splitW1<<<512, 256, 0, stream>>>(W1, W1Thi, W1Tlo);
    k_h1<<<1024, 256, 0, stream>>>(X, W1Thi, W1Tlo, b1, avec, H1TB, s1w, s2w);
    k_uv<<<32, 256, 0, stream>>>(s1w, s2w, alw, bew, uvw);
    k_packA<<<8192, 256, 0, stream>>>(A, Apk);
    k_attn<<<512, 512, 0, stream>>>(Apk, H1TB, alw, bew, uvw, H2acc, Zw);
    k_out<<<512, 256, 0, stream>>>(H2acc, Zw, Omega, beta, out);
}